// Round 11
// baseline (40962.875 us; speedup 1.0000x reference)
//
#include <hip/hip_runtime.h>
#include <math.h>

#define BB 32
#define TT 2048
#define FF 16
#define CC 17
#define HH 64

typedef float v2f __attribute__((ext_vector_type(2)));
typedef _Float16 h2 __attribute__((ext_vector_type(2)));

__device__ __forceinline__ float rl(float v, int lane) {
    return __int_as_float(__builtin_amdgcn_readlane(__float_as_int(v), lane));
}
__device__ __forceinline__ unsigned rlu(unsigned v, int lane) {
    return (unsigned)__builtin_amdgcn_readlane((int)v, lane);
}
__device__ __forceinline__ float uf(float v) {
    return __int_as_float(__builtin_amdgcn_readfirstlane(__float_as_int(v)));
}
__device__ __forceinline__ float ftanh(float x) {
    float e = __builtin_amdgcn_exp2f(x * 2.88539008177792681472f); // exp(2x)
    return 1.0f - 2.0f * __builtin_amdgcn_rcpf(e + 1.0f);
}
__device__ __forceinline__ float fdot2u(unsigned a, unsigned b, float c) {
    return __builtin_amdgcn_fdot2(__builtin_bit_cast(h2, a),
                                  __builtin_bit_cast(h2, b), c, false);
}
// pack (a,b) to f16x2, scaled by 2^8 (weights); RN; init-time only
__device__ __forceinline__ unsigned packw(float a, float b) {
    h2 p; p.x = (_Float16)(a * 256.0f); p.y = (_Float16)(b * 256.0f);
    return __builtin_bit_cast(unsigned, p);
}
// LDS-only barrier: no vmcnt(0) drain.
__device__ __forceinline__ void bar_lds() {
    asm volatile("s_waitcnt lgkmcnt(0)\n\ts_barrier" ::: "memory");
}
#define PIN(v) asm volatile("" : "+v"(v))

// R9 skeleton, but cross-wave combines use LDS ATOMIC ADD (ds_add_f32)
// accumulators instead of write-then-8-read trees. R3-R10 post-mortems: per-G
// time (~3845cy) was insensitive to VALU count / barriers / registers because
// the single LDS pipe per CU was saturated (~360 LDS instr/G ~ 2500cy at
// m134 rates). Atomic accumulation cuts LDS traffic to ~95 instr/G.
// Buffers are stage-indexed (4-deep); biases folded into the buffer init;
// wave0 re-inits stage (s-1)'s buffers one barrier after their final read.
__attribute__((amdgpu_waves_per_eu(2, 2)))
__launch_bounds__(512)
__global__ void ncde_main(const float* __restrict__ x,
                          const float* __restrict__ wi1, const float* __restrict__ bi1,
                          const float* __restrict__ wi2, const float* __restrict__ bi2,
                          const float* __restrict__ w_in, const float* __restrict__ b_in,
                          const float* __restrict__ w_hid, const float* __restrict__ b_hid,
                          const float* __restrict__ w_out, const float* __restrict__ b_out,
                          float* __restrict__ zT)
{
    const int b   = blockIdx.x;
    const int tid = threadIdx.x;
    const int w   = tid >> 6;
    const int l   = tid & 63;

    __shared__ float ph4[4][4][64];   // [stage][layer][h] accumulators (init = bias)
    __shared__ v2f  pgq4[4][64];      // [stage][h] = (pg, a16) accumulators (init = (0, bo16))

    // ---- hidden weights: wave w owns k-slice [8w,8w+8), packed 4 u32/layer ----
    unsigned whp[4][4];
    #pragma unroll
    for (int kk = 0; kk < 4; ++kk) {
        int k = 8 * w + 2 * kk;
        whp[0][kk] = packw(w_in[k * HH + l],               w_in[(k + 1) * HH + l]);
        whp[1][kk] = packw(w_hid[(0 * HH + k) * HH + l],   w_hid[(0 * HH + k + 1) * HH + l]);
        whp[2][kk] = packw(w_hid[(1 * HH + k) * HH + l],   w_hid[(1 * HH + k + 1) * HH + l]);
        whp[3][kk] = packw(w_hid[(2 * HH + k) * HH + l],   w_hid[(2 * HH + k + 1) * HH + l]);
    }
    // real biases (used only by wave 0 for accumulator init)
    float bfold[4] = { b_in[l], b_hid[0 * HH + l], b_hid[1 * HH + l], b_hid[2 * HH + l] };

    // ---- out-layer weights (cols c0,c1 per wave + c16 k-slice), packed ----
    const int c0 = 2 * w, c1 = 2 * w + 1;
    unsigned wo0p[32], wo1p[32], w16p[4];
    #pragma unroll
    for (int j = 0; j < 32; ++j) {
        wo0p[j] = packw(w_out[(2 * j) * (CC * HH) + l * CC + c0],
                        w_out[(2 * j + 1) * (CC * HH) + l * CC + c0]);
        wo1p[j] = packw(w_out[(2 * j) * (CC * HH) + l * CC + c1],
                        w_out[(2 * j + 1) * (CC * HH) + l * CC + c1]);
    }
    #pragma unroll
    for (int jj = 0; jj < 4; ++jj)
        w16p[jj] = packw(w_out[(8 * w + 2 * jj) * (CC * HH) + l * CC + 16],
                         w_out[(8 * w + 2 * jj + 1) * (CC * HH) + l * CC + 16]);
    float bo0  = b_out[l * CC + c0];
    float bo1  = b_out[l * CC + c1];
    float bo16 = b_out[l * CC + 16];

    #pragma unroll
    for (int j = 0; j < 32; ++j) { PIN(wo0p[j]); PIN(wo1p[j]); }
    #pragma unroll
    for (int jj = 0; jj < 4; ++jj) PIN(w16p[jj]);
    #pragma unroll
    for (int lay = 0; lay < 4; ++lay) {
        PIN(whp[lay][0]); PIN(whp[lay][1]); PIN(whp[lay][2]); PIN(whp[lay][3]);
    }
    PIN(bo0); PIN(bo1); PIN(bo16);

    // ---- pre-init all accumulators (bias folded in) ----
    if (w == 0) {
        #pragma unroll
        for (int s = 0; s < 4; ++s) {
            #pragma unroll
            for (int L = 0; L < 4; ++L) ph4[s][L][l] = bfold[L];
            pgq4[s][l] = (v2f){ 0.0f, bo16 };
        }
    }

    // ---- z0 = relu(xa0 @ wi1 + bi1) @ wi2 + bi2 (f32, once) ----
    float z;
    {
        float h0 = bi1[l];
        #pragma unroll
        for (int c = 1; c < CC; ++c)
            h0 = fmaf(x[(size_t)b * TT * FF + (c - 1)], wi1[c * HH + l], h0);
        h0 = fmaxf(h0, 0.0f);
        z = bi2[l];
        #pragma unroll
        for (int k = 0; k < 64; ++k)
            z = fmaf(rl(h0, k), wi2[k * HH + l], z);
    }
    if (w == 0) zT[(size_t)b * TT * HH + l] = z;
    __syncthreads();   // accumulator init visible

    // pack v*2^-8 into f16x2; every lane ends holding pair (v[2j],v[2j+1]), j=l>>1
    auto packb = [&](float v) -> unsigned {
        float hs = v * 0.00390625f;
        float pr = __shfl_xor(hs, 1);
        float a  = (l & 1) ? pr : hs;
        float bb = (l & 1) ? hs : pr;
        return __builtin_bit_cast(unsigned, __builtin_amdgcn_cvt_pkrtz(a, bb));
    };

    // ---- g(zin, xd, stage) ----
    auto G = [&](float zin, float xd0, float xd1, float xd16, int s) -> float {
        const int sp = (s + 3) & 3;   // stage whose buffers are re-initialized here
        float cur = zin;
        #pragma unroll
        for (int L = 0; L < 4; ++L) {
            unsigned hp = packb(cur);
            float a0 = 0.0f, a1 = 0.0f;
            a0 = fdot2u(rlu(hp, 8 * w + 0), whp[L][0], a0);
            a1 = fdot2u(rlu(hp, 8 * w + 2), whp[L][1], a1);
            a0 = fdot2u(rlu(hp, 8 * w + 4), whp[L][2], a0);
            a1 = fdot2u(rlu(hp, 8 * w + 6), whp[L][3], a1);
            atomicAdd(&ph4[s][L][l], a0 + a1);      // ds_add_f32, no return
            bar_lds();
            float hsum = ph4[s][L][l];               // finished sum (bias included)
            if (w == 0) ph4[sp][L][l] = bfold[L];    // re-init prev stage's buffer
            cur = fmaxf(hsum, 0.0f);
        }
        // out layer, in-wave from cur (every wave holds full h)
        unsigned hp = packb(cur);
        float u0a = 0.f, u0b = 0.f, u1a = 0.f, u1b = 0.f;
        #pragma unroll
        for (int j = 0; j < 32; j += 2) {
            unsigned s0 = rlu(hp, 2 * j);
            unsigned s1 = rlu(hp, 2 * j + 2);
            u0a = fdot2u(s0, wo0p[j],     u0a);
            u1a = fdot2u(s0, wo1p[j],     u1a);
            u0b = fdot2u(s1, wo0p[j + 1], u0b);
            u1b = fdot2u(s1, wo1p[j + 1], u1b);
        }
        float a16a = 0.f, a16b = 0.f;
        #pragma unroll
        for (int jj = 0; jj < 4; jj += 2) {
            unsigned s0 = rlu(hp, 8 * w + 2 * jj);
            unsigned s1 = rlu(hp, 8 * w + 2 * jj + 2);
            a16a = fdot2u(s0, w16p[jj],     a16a);
            a16b = fdot2u(s1, w16p[jj + 1], a16b);
        }
        float pg = ftanh(u0a + u0b + bo0) * xd0 + ftanh(u1a + u1b + bo1) * xd1;
        float* pgf = (float*)&pgq4[s][l];
        atomicAdd(pgf + 0, pg);
        atomicAdd(pgf + 1, a16a + a16b);
        bar_lds();
        v2f st = pgq4[s][l];                          // (sum pg, sum a16 + bo16)
        if (w == 0) pgq4[sp][l] = (v2f){ 0.0f, bo16 };
        return fmaf(ftanh(st.y), xd16, st.x);
    };

    // ---- time scan (uniform x scalars in SGPRs) ----
    const float* xb = x + (size_t)b * TT * FF;
    const bool hasc0 = (w != 0);
    const int  f0 = 2 * w - 1;
    const int  f1 = 2 * w;
    float xp0  = hasc0 ? uf(xb[f0]) : 0.0f;
    float xp1  = uf(xb[f1]);
    float xp16 = uf(xb[15]);
    float xn0  = hasc0 ? uf(xb[FF + f0]) : 0.0f;
    float xn1  = uf(xb[FF + f1]);
    float xn16 = uf(xb[FF + 15]);
    float dc0  = hasc0 ? (xn0 - xp0) : 1.0f;
    float dc1  = xn1 - xp1;
    float dc16 = xn16 - xp16;
    float dp0 = dc0, dp1 = dc1, dp16 = dc16;
    xp0 = xn0; xp1 = xn1; xp16 = xn16;

    #pragma unroll 1
    for (int t = 0; t < TT - 1; ++t) {
        const float f43 = 4.0f / 3.0f;
        float x20  = dp0  + f43 * (dc0  - dp0);
        float x21  = dp1  + f43 * (dc1  - dp1);
        float x216 = dp16 + f43 * (dc16 - dp16);

        int tn = (t + 2 < TT) ? (t + 2) : (TT - 1);
        float yn0  = hasc0 ? uf(xb[tn * FF + f0]) : 0.0f;
        float yn1  = uf(xb[tn * FF + f1]);
        float yn16 = uf(xb[tn * FF + 15]);

        float k1 = G(z, dp0, dp1, dp16, 0);
        float k2 = G(z + k1 * (1.0f / 3.0f), dc0, dc1, dc16, 1);
        float k3 = G(z + (k2 - k1 * (1.0f / 3.0f)), x20, x21, x216, 2);
        float k4 = G(z + (k1 - k2 + k3), dc0, dc1, dc16, 3);
        z = z + 0.125f * (k1 + 3.0f * (k2 + k3) + k4);

        if (w == 0) zT[((size_t)b * TT + t + 1) * HH + l] = z;

        dp0 = dc0; dp1 = dc1; dp16 = dc16;
        dc0 = hasc0 ? (yn0 - xp0) : 1.0f;
        dc1 = yn1 - xp1;
        dc16 = yn16 - xp16;
        xp0 = yn0; xp1 = yn1; xp16 = yn16;
    }
}

// out = gelu_exact(zT) @ w_proj + b_proj ; mask = 0
__global__ void ncde_proj(const float* __restrict__ zT,
                          const float* __restrict__ w_proj, const float* __restrict__ b_proj,
                          float* __restrict__ out, float* __restrict__ mask)
{
    __shared__ float gz[16][64];
    const int blk = blockIdx.x;
    const int tid = threadIdx.x;
    const int r16 = tid >> 4, f = tid & 15;
    const int row0 = blk * 16;

    #pragma unroll
    for (int i = 0; i < 4; ++i) {
        int idx = tid + i * 256;
        int r = idx >> 6, k = idx & 63;
        float zv = zT[(size_t)(row0 + r) * HH + k];
        gz[r][k] = 0.5f * zv * (1.0f + erff(zv * 0.70710678118654752f));
    }
    __syncthreads();

    float acc = b_proj[f];
    #pragma unroll
    for (int k = 0; k < 64; ++k)
        acc = fmaf(gz[r16][k], w_proj[k * FF + f], acc);
    out[(size_t)(row0 + r16) * FF + f] = acc;
    if (f == 0) mask[row0 + r16] = 0.0f;
}

extern "C" void kernel_launch(void* const* d_in, const int* in_sizes, int n_in,
                              void* d_out, int out_size, void* d_ws, size_t ws_size,
                              hipStream_t stream)
{
    (void)in_sizes; (void)n_in; (void)d_ws; (void)ws_size; (void)out_size;
    const float* x      = (const float*)d_in[0];
    const float* wi1    = (const float*)d_in[1];
    const float* bi1    = (const float*)d_in[2];
    const float* wi2    = (const float*)d_in[3];
    const float* bi2    = (const float*)d_in[4];
    const float* w_in   = (const float*)d_in[5];
    const float* b_in   = (const float*)d_in[6];
    const float* w_hid  = (const float*)d_in[7];
    const float* b_hid  = (const float*)d_in[8];
    const float* w_out  = (const float*)d_in[9];
    const float* b_out  = (const float*)d_in[10];
    const float* w_proj = (const float*)d_in[11];
    const float* b_proj = (const float*)d_in[12];

    float* zT   = (float*)d_out;                       // B*T*H
    float* outp = zT + (size_t)BB * TT * HH;           // B*T*F
    float* mask = outp + (size_t)BB * TT * FF;         // B*T

    ncde_main<<<dim3(BB), dim3(512), 0, stream>>>(
        x, wi1, bi1, wi2, bi2, w_in, b_in, w_hid, b_hid, w_out, b_out, zT);
    ncde_proj<<<dim3((BB * TT) / 16), dim3(256), 0, stream>>>(
        zT, w_proj, b_proj, outp, mask);
}

// Round 12
// 12856.169 us; speedup vs baseline: 3.1862x; 3.1862x over previous
//
#include <hip/hip_runtime.h>
#include <math.h>

#define BB 32
#define TT 2048
#define FF 16
#define CC 17
#define HH 64

typedef float v2f __attribute__((ext_vector_type(2)));
typedef float v4f __attribute__((ext_vector_type(4)));
typedef _Float16 h2 __attribute__((ext_vector_type(2)));

__device__ __forceinline__ float rl(float v, int lane) {
    return __int_as_float(__builtin_amdgcn_readlane(__float_as_int(v), lane));
}
__device__ __forceinline__ unsigned rlu(unsigned v, int lane) {
    return (unsigned)__builtin_amdgcn_readlane((int)v, lane);
}
__device__ __forceinline__ float uf(float v) {
    return __int_as_float(__builtin_amdgcn_readfirstlane(__float_as_int(v)));
}
__device__ __forceinline__ float ftanh(float x) {
    float e = __builtin_amdgcn_exp2f(x * 2.88539008177792681472f); // exp(2x)
    return 1.0f - 2.0f * __builtin_amdgcn_rcpf(e + 1.0f);
}
__device__ __forceinline__ float fdot2u(unsigned a, unsigned b, float c) {
    return __builtin_amdgcn_fdot2(__builtin_bit_cast(h2, a),
                                  __builtin_bit_cast(h2, b), c, false);
}
// pack (a,b) to f16x2, scaled by 2^8 (weights); RN; init-time only
__device__ __forceinline__ unsigned packw(float a, float b) {
    h2 p; p.x = (_Float16)(a * 256.0f); p.y = (_Float16)(b * 256.0f);
    return __builtin_bit_cast(unsigned, p);
}
// LDS-only barrier: no vmcnt(0) drain.
__device__ __forceinline__ void bar_lds() {
    asm volatile("s_waitcnt lgkmcnt(0)\n\ts_barrier" ::: "memory");
}
#define PIN(v) asm volatile("" : "+v"(v))

// R9 skeleton with TRANSPOSED combine buffers (no atomics):
//   wave w writes its partial for h[l] at pht[L][l][col]; each lane reads its
//   own ROW contiguously -> 2 x ds_read_b128 replaces 8 x ds_read_b32.
//   (pg,a16) combine: 1 b64 write + 4 b128 reads replaces 1+8 b64.
// LDS instr/G: 360 -> 136 (theory: the single LDS pipe/CU at ~2300cy/G was the
// binding constraint R3-R9; atomics (R11) serialized same-address and lost).
// Row stride 12 floats: every b128 16B-aligned, bank starts spread.
// Column XOR-swizzle (w ^ ((l>>3)&7)): kills the 8-way write conflict; legal
// because the row is only ever SUMMED (order-invariant).
__attribute__((amdgpu_waves_per_eu(2, 2)))
__launch_bounds__(512)
__global__ void ncde_main(const float* __restrict__ x,
                          const float* __restrict__ wi1, const float* __restrict__ bi1,
                          const float* __restrict__ wi2, const float* __restrict__ bi2,
                          const float* __restrict__ w_in, const float* __restrict__ b_in,
                          const float* __restrict__ w_hid, const float* __restrict__ b_hid,
                          const float* __restrict__ w_out, const float* __restrict__ b_out,
                          float* __restrict__ zT)
{
    const int b   = blockIdx.x;
    const int tid = threadIdx.x;
    const int w   = tid >> 6;
    const int l   = tid & 63;

    __shared__ float pht[4][64][12];   // [layer][h-row][wave-col + pad]
    __shared__ float pgqt[64][20];     // [h-row][(pg,a16) x 8 wave-cols + pad]

    const int cs = w ^ ((l >> 3) & 7);   // swizzled column (order-invariant sum)

    // ---- hidden weights: wave w owns k-slice [8w,8w+8), packed 4 u32/layer ----
    unsigned whp[4][4];
    #pragma unroll
    for (int kk = 0; kk < 4; ++kk) {
        int k = 8 * w + 2 * kk;
        whp[0][kk] = packw(w_in[k * HH + l],               w_in[(k + 1) * HH + l]);
        whp[1][kk] = packw(w_hid[(0 * HH + k) * HH + l],   w_hid[(0 * HH + k + 1) * HH + l]);
        whp[2][kk] = packw(w_hid[(1 * HH + k) * HH + l],   w_hid[(1 * HH + k + 1) * HH + l]);
        whp[3][kk] = packw(w_hid[(2 * HH + k) * HH + l],   w_hid[(2 * HH + k + 1) * HH + l]);
    }
    float bfold[4];
    bfold[0] = (w == 0) ? b_in[l] : 0.0f;
    bfold[1] = (w == 0) ? b_hid[0 * HH + l] : 0.0f;
    bfold[2] = (w == 0) ? b_hid[1 * HH + l] : 0.0f;
    bfold[3] = (w == 0) ? b_hid[2 * HH + l] : 0.0f;

    // ---- out-layer weights (cols c0,c1 per wave + c16 k-slice), packed ----
    const int c0 = 2 * w, c1 = 2 * w + 1;
    unsigned wo0p[32], wo1p[32], w16p[4];
    #pragma unroll
    for (int j = 0; j < 32; ++j) {
        wo0p[j] = packw(w_out[(2 * j) * (CC * HH) + l * CC + c0],
                        w_out[(2 * j + 1) * (CC * HH) + l * CC + c0]);
        wo1p[j] = packw(w_out[(2 * j) * (CC * HH) + l * CC + c1],
                        w_out[(2 * j + 1) * (CC * HH) + l * CC + c1]);
    }
    #pragma unroll
    for (int jj = 0; jj < 4; ++jj)
        w16p[jj] = packw(w_out[(8 * w + 2 * jj) * (CC * HH) + l * CC + 16],
                         w_out[(8 * w + 2 * jj + 1) * (CC * HH) + l * CC + 16]);
    float bo0  = b_out[l * CC + c0];
    float bo1  = b_out[l * CC + c1];
    float bo16 = (w == 0) ? b_out[l * CC + 16] : 0.0f;   // folded into wave0 partial

    #pragma unroll
    for (int j = 0; j < 32; ++j) { PIN(wo0p[j]); PIN(wo1p[j]); }
    #pragma unroll
    for (int jj = 0; jj < 4; ++jj) PIN(w16p[jj]);
    #pragma unroll
    for (int lay = 0; lay < 4; ++lay) {
        PIN(whp[lay][0]); PIN(whp[lay][1]); PIN(whp[lay][2]); PIN(whp[lay][3]);
    }
    PIN(bo0); PIN(bo1); PIN(bo16);

    // ---- z0 = relu(xa0 @ wi1 + bi1) @ wi2 + bi2 (f32, once) ----
    float z;
    {
        float h0 = bi1[l];
        #pragma unroll
        for (int c = 1; c < CC; ++c)
            h0 = fmaf(x[(size_t)b * TT * FF + (c - 1)], wi1[c * HH + l], h0);
        h0 = fmaxf(h0, 0.0f);
        z = bi2[l];
        #pragma unroll
        for (int k = 0; k < 64; ++k)
            z = fmaf(rl(h0, k), wi2[k * HH + l], z);
    }
    if (w == 0) zT[(size_t)b * TT * HH + l] = z;

    // pack v*2^-8 into f16x2; every lane ends holding pair (v[2j],v[2j+1]), j=l>>1
    auto packb = [&](float v) -> unsigned {
        float hs = v * 0.00390625f;
        float pr = __shfl_xor(hs, 1);
        float a  = (l & 1) ? pr : hs;
        float bb = (l & 1) ? hs : pr;
        return __builtin_bit_cast(unsigned, __builtin_amdgcn_cvt_pkrtz(a, bb));
    };

    // ---- g(zin, xd) ----
    auto G = [&](float zin, float xd0, float xd1, float xd16) -> float {
        float cur = zin;
        #pragma unroll
        for (int L = 0; L < 4; ++L) {
            unsigned hp = packb(cur);
            float a0 = bfold[L], a1 = 0.0f;
            a0 = fdot2u(rlu(hp, 8 * w + 0), whp[L][0], a0);
            a1 = fdot2u(rlu(hp, 8 * w + 2), whp[L][1], a1);
            a0 = fdot2u(rlu(hp, 8 * w + 4), whp[L][2], a0);
            a1 = fdot2u(rlu(hp, 8 * w + 6), whp[L][3], a1);
            pht[L][l][cs] = a0 + a1;
            bar_lds();
            const float* row = &pht[L][l][0];
            v4f q0 = *reinterpret_cast<const v4f*>(row);       // cols 0..3 (any order)
            v4f q1 = *reinterpret_cast<const v4f*>(row + 4);   // cols 4..7
            float hsum = ((q0.x + q0.y) + (q0.z + q0.w)) + ((q1.x + q1.y) + (q1.z + q1.w));
            cur = fmaxf(hsum, 0.0f);
        }
        // out layer, fully in-wave from cur (every wave holds full h)
        unsigned hp = packb(cur);
        float u0a = 0.f, u0b = 0.f, u1a = 0.f, u1b = 0.f;
        #pragma unroll
        for (int j = 0; j < 32; j += 2) {
            unsigned s0 = rlu(hp, 2 * j);
            unsigned s1 = rlu(hp, 2 * j + 2);
            u0a = fdot2u(s0, wo0p[j],     u0a);
            u1a = fdot2u(s0, wo1p[j],     u1a);
            u0b = fdot2u(s1, wo0p[j + 1], u0b);
            u1b = fdot2u(s1, wo1p[j + 1], u1b);
        }
        float a16a = bo16, a16b = 0.f;
        #pragma unroll
        for (int jj = 0; jj < 4; jj += 2) {
            unsigned s0 = rlu(hp, 8 * w + 2 * jj);
            unsigned s1 = rlu(hp, 8 * w + 2 * jj + 2);
            a16a = fdot2u(s0, w16p[jj],     a16a);
            a16b = fdot2u(s1, w16p[jj + 1], a16b);
        }
        float pg = ftanh(u0a + u0b + bo0) * xd0 + ftanh(u1a + u1b + bo1) * xd1;
        *reinterpret_cast<v2f*>(&pgqt[l][2 * cs]) = (v2f){ pg, a16a + a16b };
        bar_lds();
        const float* prow = &pgqt[l][0];
        v4f r0 = *reinterpret_cast<const v4f*>(prow);
        v4f r1 = *reinterpret_cast<const v4f*>(prow + 4);
        v4f r2 = *reinterpret_cast<const v4f*>(prow + 8);
        v4f r3 = *reinterpret_cast<const v4f*>(prow + 12);
        float pgs  = ((r0.x + r0.z) + (r1.x + r1.z)) + ((r2.x + r2.z) + (r3.x + r3.z));
        float a16s = ((r0.y + r0.w) + (r1.y + r1.w)) + ((r2.y + r2.w) + (r3.y + r3.w));
        return fmaf(ftanh(a16s), xd16, pgs);
    };

    // ---- time scan (uniform x scalars in SGPRs) ----
    const float* xb = x + (size_t)b * TT * FF;
    const bool hasc0 = (w != 0);
    const int  f0 = 2 * w - 1;
    const int  f1 = 2 * w;
    float xp0  = hasc0 ? uf(xb[f0]) : 0.0f;
    float xp1  = uf(xb[f1]);
    float xp16 = uf(xb[15]);
    float xn0  = hasc0 ? uf(xb[FF + f0]) : 0.0f;
    float xn1  = uf(xb[FF + f1]);
    float xn16 = uf(xb[FF + 15]);
    float dc0  = hasc0 ? (xn0 - xp0) : 1.0f;
    float dc1  = xn1 - xp1;
    float dc16 = xn16 - xp16;
    float dp0 = dc0, dp1 = dc1, dp16 = dc16;
    xp0 = xn0; xp1 = xn1; xp16 = xn16;

    #pragma unroll 1
    for (int t = 0; t < TT - 1; ++t) {
        const float f43 = 4.0f / 3.0f;
        float x20  = dp0  + f43 * (dc0  - dp0);
        float x21  = dp1  + f43 * (dc1  - dp1);
        float x216 = dp16 + f43 * (dc16 - dp16);

        int tn = (t + 2 < TT) ? (t + 2) : (TT - 1);
        float yn0  = hasc0 ? uf(xb[tn * FF + f0]) : 0.0f;
        float yn1  = uf(xb[tn * FF + f1]);
        float yn16 = uf(xb[tn * FF + 15]);

        float k1 = G(z, dp0, dp1, dp16);
        float k2 = G(z + k1 * (1.0f / 3.0f), dc0, dc1, dc16);
        float k3 = G(z + (k2 - k1 * (1.0f / 3.0f)), x20, x21, x216);
        float k4 = G(z + (k1 - k2 + k3), dc0, dc1, dc16);
        z = z + 0.125f * (k1 + 3.0f * (k2 + k3) + k4);

        if (w == 0) zT[((size_t)b * TT + t + 1) * HH + l] = z;

        dp0 = dc0; dp1 = dc1; dp16 = dc16;
        dc0 = hasc0 ? (yn0 - xp0) : 1.0f;
        dc1 = yn1 - xp1;
        dc16 = yn16 - xp16;
        xp0 = yn0; xp1 = yn1; xp16 = yn16;
    }
}

// out = gelu_exact(zT) @ w_proj + b_proj ; mask = 0
__global__ void ncde_proj(const float* __restrict__ zT,
                          const float* __restrict__ w_proj, const float* __restrict__ b_proj,
                          float* __restrict__ out, float* __restrict__ mask)
{
    __shared__ float gz[16][64];
    const int blk = blockIdx.x;
    const int tid = threadIdx.x;
    const int r16 = tid >> 4, f = tid & 15;
    const int row0 = blk * 16;

    #pragma unroll
    for (int i = 0; i < 4; ++i) {
        int idx = tid + i * 256;
        int r = idx >> 6, k = idx & 63;
        float zv = zT[(size_t)(row0 + r) * HH + k];
        gz[r][k] = 0.5f * zv * (1.0f + erff(zv * 0.70710678118654752f));
    }
    __syncthreads();

    float acc = b_proj[f];
    #pragma unroll
    for (int k = 0; k < 64; ++k)
        acc = fmaf(gz[r16][k], w_proj[k * FF + f], acc);
    out[(size_t)(row0 + r16) * FF + f] = acc;
    if (f == 0) mask[row0 + r16] = 0.0f;
}

extern "C" void kernel_launch(void* const* d_in, const int* in_sizes, int n_in,
                              void* d_out, int out_size, void* d_ws, size_t ws_size,
                              hipStream_t stream)
{
    (void)in_sizes; (void)n_in; (void)d_ws; (void)ws_size; (void)out_size;
    const float* x      = (const float*)d_in[0];
    const float* wi1    = (const float*)d_in[1];
    const float* bi1    = (const float*)d_in[2];
    const float* wi2    = (const float*)d_in[3];
    const float* bi2    = (const float*)d_in[4];
    const float* w_in   = (const float*)d_in[5];
    const float* b_in   = (const float*)d_in[6];
    const float* w_hid  = (const float*)d_in[7];
    const float* b_hid  = (const float*)d_in[8];
    const float* w_out  = (const float*)d_in[9];
    const float* b_out  = (const float*)d_in[10];
    const float* w_proj = (const float*)d_in[11];
    const float* b_proj = (const float*)d_in[12];

    float* zT   = (float*)d_out;                       // B*T*H
    float* outp = zT + (size_t)BB * TT * HH;           // B*T*F
    float* mask = outp + (size_t)BB * TT * FF;         // B*T

    ncde_main<<<dim3(BB), dim3(512), 0, stream>>>(
        x, wi1, bi1, wi2, bi2, w_in, b_in, w_hid, b_hid, w_out, b_out, zT);
    ncde_proj<<<dim3((BB * TT) / 16), dim3(256), 0, stream>>>(
        zT, w_proj, b_proj, outp, mask);
}